// Round 1
// baseline (48.205 us; speedup 1.0000x reference)
//
#include <hip/hip_runtime.h>

typedef unsigned short u16;
typedef __attribute__((ext_vector_type(8))) short bf16x8;
typedef __attribute__((ext_vector_type(4))) float f32x4;

#define N_ROWS 131072
#define FDIM 32
#define RDIM 256
#define ODIM 5
#define NOUT 100
#define JT 7               // ceil(100/16) output col tiles (padded to 112)
#define KST 8              // 256 / 32 k-steps for GEMM2
#define WAVES 8
#define TPW 2              // 16-row tiles per wave
#define ROWS_PER_BLOCK (WAVES * TPW * 16)   // 256
#define NBLOCKS (N_ROWS / ROWS_PER_BLOCK)   // 512

__device__ __forceinline__ u16 f2bf(float f) {
    union { float f; unsigned u; } v; v.f = f;
    return (u16)((v.u + 0x7FFFu + ((v.u >> 16) & 1u)) >> 16);  // RNE
}

// ---------------------------------------------------------------------------
// K1: build M fragments in exact B-operand lane order for mfma_f32_16x16x32_bf16.
// M[k][r] = comb_space[o][r] if comb_idx[r][o]==k else 0.
// mf[(rt*64+lane)*8 + e] = M[(lane>>4)*8+e][rt*16+(lane&15)]
// ---------------------------------------------------------------------------
__global__ void build_mfrag(const float* __restrict__ cs, const int* __restrict__ ci,
                            u16* __restrict__ mf) {
    int t = blockIdx.x * blockDim.x + threadIdx.x;   // 0..1023
    if (t >= 16 * 64) return;
    int lane = t & 63;
    int rt = t >> 6;
    int r = rt * 16 + (lane & 15);
    int kbase = (lane >> 4) * 8;
#pragma unroll
    for (int e = 0; e < 8; ++e) {
        int k = kbase + e;
        float v = 0.f;
#pragma unroll
        for (int o = 0; o < ODIM; ++o)
            if (ci[r * ODIM + o] == k) v = cs[o * RDIM + r];
        mf[t * 8 + e] = f2bf(v);
    }
}

// ---------------------------------------------------------------------------
// K2: build w^T fragments (B-operand of GEMM2), bf16, j padded to 112.
// wf[((jt*8+ks)*64+lane)*8 + e] = w_out[jt*16+(lane&15)][ks*32+(lane>>4)*8+e]
// ---------------------------------------------------------------------------
__global__ void build_wfrag(const float* __restrict__ w, u16* __restrict__ wf) {
    int t = blockIdx.x * blockDim.x + threadIdx.x;   // 0..3583
    if (t >= JT * KST * 64) return;
    int lane = t & 63;
    int jt = (t >> 6) >> 3;
    int ks = (t >> 6) & 7;
    int j = jt * 16 + (lane & 15);
    int rbase = ks * 32 + (lane >> 4) * 8;
#pragma unroll
    for (int e = 0; e < 8; ++e) {
        float v = (j < NOUT) ? w[j * RDIM + rbase + e] : 0.f;
        wf[t * 8 + e] = f2bf(v);
    }
}

// ---------------------------------------------------------------------------
// Main fused kernel. Per 16-row tile (one wave):
//   GEMM1: scores(16x256) = x(16x32,bf16) @ M(32x256,bf16)   [16 MFMA]
//   pred = clip(scores^9,±1); e = exp(pred)  (pred∈[-1,1] → no max needed)
//   GEMM2: out_un(16x112) = E(16x256,bf16) @ w^T              [56 MFMA]
//   out = out_un/S + b;  log_softmax over 100;  store f32.
// ---------------------------------------------------------------------------
__global__ __launch_bounds__(WAVES * 64, 2) void hornet_main(
    const float* __restrict__ x, const u16* __restrict__ mfg,
    const u16* __restrict__ wfg, const float* __restrict__ b_out,
    float* __restrict__ out)
{
    __shared__ __align__(16) u16 mf[16 * 64 * 8];            // 16 KB
    __shared__ __align__(16) u16 wf[JT * KST * 64 * 8];      // 57.3 KB
    __shared__ __align__(16) u16 pf[WAVES][KST * 64 * 8];    // 64 KB

    const int tid = threadIdx.x;
    const int wid = tid >> 6;
    const int lane = tid & 63;

    // stage fragment tables (coalesced uint4 copies)
    {
        const uint4* ms = (const uint4*)mfg;
        uint4* md = (uint4*)mf;
        for (int i = tid; i < 16 * 64 * 8 / 8; i += WAVES * 64) md[i] = ms[i];
        const uint4* wsrc = (const uint4*)wfg;
        uint4* wd = (uint4*)wf;
        for (int i = tid; i < JT * KST * 64 * 8 / 8; i += WAVES * 64) wd[i] = wsrc[i];
    }
    __syncthreads();

    // per-lane bias values (b_out is tiny, L1/L2 resident)
    float bv[JT];
#pragma unroll
    for (int jt = 0; jt < JT; ++jt) {
        int j = jt * 16 + (lane & 15);
        bv[jt] = (j < NOUT) ? b_out[j] : 0.f;
    }

    u16* mypf = pf[wid];

    for (int t = 0; t < TPW; ++t) {
        const int rowbase = blockIdx.x * ROWS_PER_BLOCK + (wid * TPW + t) * 16;

        // A1 fragment: x[rowbase+(lane&15)][(lane>>4)*8 + 0..7], exact in bf16
        const float* xp = x + (size_t)(rowbase + (lane & 15)) * FDIM + (lane >> 4) * 8;
        float4 xa = ((const float4*)xp)[0];
        float4 xb = ((const float4*)xp)[1];
        bf16x8 a1;
        a1[0] = (short)f2bf(xa.x); a1[1] = (short)f2bf(xa.y);
        a1[2] = (short)f2bf(xa.z); a1[3] = (short)f2bf(xa.w);
        a1[4] = (short)f2bf(xb.x); a1[5] = (short)f2bf(xb.y);
        a1[6] = (short)f2bf(xb.z); a1[7] = (short)f2bf(xb.w);

        f32x4 rs = {0.f, 0.f, 0.f, 0.f};   // per-lane partial row sums of e
#pragma unroll
        for (int rt = 0; rt < 16; ++rt) {
            bf16x8 b1 = *(const bf16x8*)(mf + (rt * 64 + lane) * 8);
            f32x4 c = {0.f, 0.f, 0.f, 0.f};
            c = __builtin_amdgcn_mfma_f32_16x16x32_bf16(a1, b1, c, 0, 0, 0);
            // C layout: row=(lane>>4)*4+i, col r = rt*16+(lane&15)
            int r = rt * 16 + (lane & 15);
            int ks = r >> 5;
            int l2base = ((r >> 3) & 3) * 16;
            int e = r & 7;
#pragma unroll
            for (int i = 0; i < 4; ++i) {
                float s = c[i];
                float s2 = s * s, s4 = s2 * s2, s8 = s4 * s4;
                float p = s8 * s;                       // s^9
                p = fminf(fmaxf(p, -1.f), 1.f);
                float ev = __expf(p);
                rs[i] += ev;
                int row = (lane >> 4) * 4 + i;
                // store into A2-fragment order: pf[(ks*64+l')*8 + (r&7)], l' = row + 16*((r>>3)&3)
                mypf[(ks * 64 + l2base + row) * 8 + e] = f2bf(ev);
            }
        }
        __syncthreads();   // order pf writes before A2 reads (uniform across waves)

        // preload A2 fragments (this wave's 16 rows x 256 r, bf16)
        bf16x8 a2[KST];
#pragma unroll
        for (int k = 0; k < KST; ++k)
            a2[k] = *(const bf16x8*)(mypf + (k * 64 + lane) * 8);

        f32x4 acc[JT];
#pragma unroll
        for (int jt = 0; jt < JT; ++jt) acc[jt] = (f32x4){0.f, 0.f, 0.f, 0.f};
#pragma unroll
        for (int jt = 0; jt < JT; ++jt)
#pragma unroll
            for (int k = 0; k < KST; ++k) {
                bf16x8 b2 = *(const bf16x8*)(wf + ((jt * KST + k) * 64 + lane) * 8);
                acc[jt] = __builtin_amdgcn_mfma_f32_16x16x32_bf16(a2[k], b2, acc[jt], 0, 0, 0);
            }

        // full row sums: reduce rs across the 16 lanes of each (lane>>4) group
#pragma unroll
        for (int m = 1; m <= 8; m <<= 1) {
#pragma unroll
            for (int i = 0; i < 4; ++i) rs[i] += __shfl_xor(rs[i], m, 64);
        }
        f32x4 rinv;
#pragma unroll
        for (int i = 0; i < 4; ++i) rinv[i] = 1.f / rs[i];

        // epilogue: scale, bias, log_softmax over j (valid j<100), store
        const int jcol = lane & 15;
#pragma unroll
        for (int i = 0; i < 4; ++i) {
            float lg[JT];
            float mx = -3.0e38f;
#pragma unroll
            for (int jt = 0; jt < JT; ++jt) {
                bool valid = (jt < 6) || (jcol < 4);
                lg[jt] = valid ? (acc[jt][i] * rinv[i] + bv[jt]) : -3.0e38f;
                mx = fmaxf(mx, lg[jt]);
            }
#pragma unroll
            for (int m = 1; m <= 8; m <<= 1) mx = fmaxf(mx, __shfl_xor(mx, m, 64));
            float se = 0.f;
#pragma unroll
            for (int jt = 0; jt < JT; ++jt) {
                bool valid = (jt < 6) || (jcol < 4);
                if (valid) se += __expf(lg[jt] - mx);
            }
#pragma unroll
            for (int m = 1; m <= 8; m <<= 1) se += __shfl_xor(se, m, 64);
            float lse = __logf(se);
            int row = rowbase + (lane >> 4) * 4 + i;
            float* op = out + (size_t)row * NOUT;
#pragma unroll
            for (int jt = 0; jt < JT; ++jt) {
                bool valid = (jt < 6) || (jcol < 4);
                if (valid) op[jt * 16 + jcol] = lg[jt] - mx - lse;
            }
        }
    }
}

extern "C" void kernel_launch(void* const* d_in, const int* in_sizes, int n_in,
                              void* d_out, int out_size, void* d_ws, size_t ws_size,
                              hipStream_t stream) {
    const float* x  = (const float*)d_in[0];
    const float* cs = (const float*)d_in[1];
    const float* w  = (const float*)d_in[2];
    const float* b  = (const float*)d_in[3];
    const int*   ci = (const int*)d_in[4];

    u16* mfg = (u16*)d_ws;             // 8192 u16 = 16 KB
    u16* wfg = mfg + 16 * 64 * 8;      // 28672 u16 = 57.3 KB  (total ws use: 73.7 KB)

    hipLaunchKernelGGL(build_mfrag, dim3(4), dim3(256), 0, stream, cs, ci, mfg);
    hipLaunchKernelGGL(build_wfrag, dim3(14), dim3(256), 0, stream, w, wfg);
    hipLaunchKernelGGL(hornet_main, dim3(NBLOCKS), dim3(WAVES * 64), 0, stream,
                       x, mfg, wfg, b, (float*)d_out);
}